// Round 3
// baseline (5784.983 us; speedup 1.0000x reference)
//
#include <hip/hip_runtime.h>
#include <math.h>

#define NROWS 2048
#define KNEI  8
#define LSEQ  64
#define HD    512
#define HD4   128
#define HDP   (HD+8)
#define LATD  128
#define NHPN  4
#define NNUC  5

typedef __attribute__((ext_vector_type(8))) short s8b;   // 8 bf16 (16B)
typedef __attribute__((ext_vector_type(4))) short s4b;   // 4 bf16 (8B)
typedef __attribute__((ext_vector_type(4))) float f4;    // MFMA acc

#define MFMA16(a,b,c) __builtin_amdgcn_mfma_f32_16x16x32_bf16(a,b,c,0,0,0)
#define WAITV4 asm volatile("s_waitcnt vmcnt(4)" ::: "memory")
#define LGKM0  asm volatile("s_waitcnt lgkmcnt(0)" ::: "memory")
#define BAR()  asm volatile("s_waitcnt lgkmcnt(0)\ns_barrier" ::: "memory")

__device__ __forceinline__ float sigf(float x){ return __fdividef(1.0f, 1.0f + __expf(-x)); }
__device__ __forceinline__ float tanhf_fast(float x){
  float e = __expf(-2.0f*fabsf(x));
  float t = __fdividef(1.0f - e, 1.0f + e);
  return x >= 0.f ? t : -t;
}
__device__ __forceinline__ unsigned short f2bf(float x){
  union{float f; unsigned u;} v; v.f = x;
  unsigned r = (v.u + 0x7FFFu + ((v.u>>16)&1u)) >> 16;
  return (unsigned short)r;
}
__device__ __forceinline__ float bf2f(unsigned short u){
  union{unsigned x; float f;} v; v.x = ((unsigned)u)<<16; return v.f;
}
__device__ __forceinline__ float bflo(unsigned u){ union{unsigned x; float f;} v; v.x = u<<16; return v.f; }
__device__ __forceinline__ float bfhi(unsigned u){ union{unsigned x; float f;} v; v.x = u & 0xFFFF0000u; return v.f; }

__device__ __forceinline__ void dma16(const short* g, const short* l){
  __builtin_amdgcn_global_load_lds(
      (const __attribute__((address_space(1))) void*)(unsigned long long)g,
      (__attribute__((address_space(3))) void*)(unsigned long long)l,
      16, 0, 0);
}
__device__ __forceinline__ void issue4(const short* glane, int tile, const short* slotBase){
  #pragma unroll
  for (int u=0;u<4;++u)
    dma16(glane + (size_t)(tile+u)*512, slotBase + u*512);
}

// ----- fp32 helpers for graphgru (unchanged from round 2) -----
__device__ __forceinline__ void fma4(float4& a, float s, float4 w){
  a.x = fmaf(s,w.x,a.x); a.y = fmaf(s,w.y,a.y); a.z = fmaf(s,w.z,a.z); a.w = fmaf(s,w.w,a.w);
}
__device__ __forceinline__ void add4(float4& a, float4 b){ a.x+=b.x; a.y+=b.y; a.z+=b.z; a.w+=b.w; }
__device__ __forceinline__ float4 sig4(float4 v){
  return make_float4(1.f/(1.f+__expf(-v.x)),1.f/(1.f+__expf(-v.y)),1.f/(1.f+__expf(-v.z)),1.f/(1.f+__expf(-v.w)));
}
__device__ __forceinline__ float4 relu4(float4 v){ return make_float4(fmaxf(v.x,0.f),fmaxf(v.y,0.f),fmaxf(v.z,0.f),fmaxf(v.w,0.f)); }
__device__ __forceinline__ float dot4(float4 a, float4 b){ return a.x*b.x + a.y*b.y + a.z*b.z + a.w*b.w; }
__device__ __forceinline__ float4 gate_mul(float4 tv, float4 e){
  return make_float4((1.f/(1.f+__expf(-tv.x)))*e.x,(1.f/(1.f+__expf(-tv.y)))*e.y,
                     (1.f/(1.f+__expf(-tv.z)))*e.z,(1.f/(1.f+__expf(-tv.w)))*e.w);
}
__device__ __forceinline__ float4 gru_out(float4 z, float4 hprev, float4 pre){
  return make_float4((1.f-z.x)*hprev.x + z.x*tanhf(pre.x),
                     (1.f-z.y)*hprev.y + z.y*tanhf(pre.y),
                     (1.f-z.z)*hprev.z + z.z*tanhf(pre.z),
                     (1.f-z.w)*hprev.w + z.w*tanhf(pre.w));
}

// ---------------- prep kernels ----------------

__global__ void transpose_w(const float* __restrict__ src, float* __restrict__ dst,
                            int src_cols, int col_off, int nh){
  int idx = blockIdx.x*256 + threadIdx.x;
  if (idx >= nh*HD) return;
  int h = idx / HD, o = idx - h*HD;
  dst[idx] = src[o*src_cols + col_off + h];
}

// A-frag layout (per 16x16 tile, 1KB): dst[tile*512 + l*8 + j] = W[row][k]
// row = ot*16+(l&15), k = kc*32+(l>>4)*8+j
__global__ void fragprep_k(const float* __restrict__ W, short* __restrict__ dst,
                           int src_cols, int col_off){
  int idx = blockIdx.x*256 + threadIdx.x;
  if (idx >= HD*HD) return;
  int j = idx&7, l = (idx>>3)&63, tile = idx>>9;
  int kc = tile&15, ot = tile>>4;
  int row = ot*16 + (l&15), k = kc*32 + (l>>4)*8 + j;
  dst[idx] = (short)f2bf(W[(size_t)row*src_cols + col_off + k]);
}

// flattened per-wave weight stream for the scan:
// stream[w][T][512] ; T<128: kc=T>>3, m=T&7 (m<4: z ot=4w+m ; else r ot=4w+m-4)
// 128<=T<192: h ; 192<=T<256: nuc head.  tile content = A-frag layout above.
__global__ void streamprep_k(const float* __restrict__ Wz, const float* __restrict__ Wr,
                             const float* __restrict__ Wh, const float* __restrict__ Wn,
                             short* __restrict__ stream){
  int idx = blockIdx.x*256 + threadIdx.x;
  if (idx >= 8*256*512) return;
  int s = idx & 511;
  int T = (idx >> 9) & 255;
  int w = idx >> 17;
  int j = s & 7, l = s >> 3;
  int kc, i, sc, co; const float* W;
  if (T < 128){
    kc = T >> 3; int m = T & 7;
    if (m < 4){ W = Wz; i = m; } else { W = Wr; i = m - 4; }
    sc = HD+NNUC; co = NNUC;
  } else if (T < 192){
    int u = T - 128; kc = u >> 2; i = u & 3; W = Wh; sc = HD+NNUC; co = NNUC;
  } else {
    int u = T - 192; kc = u >> 2; i = u & 3; W = Wn; sc = HD+LATD; co = 0;
  }
  int ot = 4*w + i;
  int row = ot*16 + (l & 15);
  int k   = kc*32 + (l >> 4)*8 + j;
  stream[idx] = (short)f2bf(W[(size_t)row*sc + co + k]);
}

// wxb[c*HD + n] = W[n][c] + b[n]
__global__ void wxbprep_k(const float* __restrict__ W, const float* __restrict__ b,
                          float* __restrict__ dst, int src_cols){
  int idx = blockIdx.x*256 + threadIdx.x;
  if (idx >= NNUC*HD) return;
  int c = idx/HD, n = idx - c*HD;
  dst[idx] = W[(size_t)n*src_cols + c] + b[n];
}

// latp[n][o] = b_nl[o] + sum_q gl[n][q]*wtlat[q*HD+o]   (128 blocks x 16 rows)
__global__ __launch_bounds__(512) void latp_k(const float* __restrict__ gl, const float* __restrict__ wtlat,
                     const float* __restrict__ bnl, float* __restrict__ latp){
  __shared__ float gls[16][LATD];
  int b = blockIdx.x, t = threadIdx.x;
  for (int i=t;i<16*LATD;i+=512) gls[i/LATD][i%LATD] = gl[(size_t)(b*16)*LATD + i];
  __syncthreads();
  float acc[16];
  float bv = bnl[t];
  #pragma unroll
  for (int r=0;r<16;++r) acc[r]=bv;
  for (int q=0;q<LATD;++q){
    float wv = wtlat[(size_t)q*HD + t];
    #pragma unroll
    for (int r=0;r<16;++r) acc[r] = fmaf(gls[r][q], wv, acc[r]);
  }
  #pragma unroll
  for (int r=0;r<16;++r) latp[(size_t)(b*16+r)*HD + t] = acc[r];
}

// ---------------- GraphGRU (unchanged fp32 path) ----------------
__global__ __launch_bounds__(512) void graphgru_k(
    const int* __restrict__ hpn_idx, const float* __restrict__ h_nei,
    const float* __restrict__ wt_z, const float* __restrict__ wx_z, const float* __restrict__ bz,
    const float* __restrict__ wx_r, const float* __restrict__ br,
    const float* __restrict__ wt_ur,
    const float* __restrict__ wt_h, const float* __restrict__ wx_h, const float* __restrict__ bh,
    const float* __restrict__ wt_topo, const float* __restrict__ b_topo_nl,
    const float* __restrict__ w_topo, const float* __restrict__ b_topo,
    float* __restrict__ msg, float* __restrict__ out_stop)
{
  __shared__ float sumh[8][HD];
  __shared__ float hk[8][HD];
  __shared__ float sg[8][HD];
  __shared__ float red[8][2];
  const int t = threadIdx.x, lane = t&63, wv = t>>6;
  const int r0 = (wv>>1)<<1;
  const int oh = wv&1;
  const int ob4 = 64*oh + lane;
  const int n0 = blockIdx.x*8;
  float4* sumh4 = (float4*)(&sumh[0][0]);
  float4* hk4   = (float4*)(&hk[0][0]);
  float4* sg4   = (float4*)(&sg[0][0]);
  const float4* hn4 = (const float4*)h_nei;

  for (int idx=t; idx<8*HD4; idx+=512){
    int r = idx>>7, c = idx&127;
    size_t base = ((size_t)(n0+r))*KNEI*HD4 + c;
    float4 s = hn4[base];
    #pragma unroll
    for (int k=1;k<KNEI;++k) add4(s, hn4[base + (size_t)k*HD4]);
    sumh4[idx] = s;
  }
  __syncthreads();

  const int hp0 = hpn_idx[n0+r0], hp1 = hpn_idx[n0+r0+1];
  const float4* bz4 = (const float4*)bz;
  const float4* wxz4 = (const float4*)wx_z;
  const float4* wtz4 = (const float4*)wt_z;
  float4 z0 = bz4[ob4]; add4(z0, wxz4[hp0*HD4 + ob4]);
  float4 z1 = bz4[ob4]; add4(z1, wxz4[hp1*HD4 + ob4]);
  for (int h=0;h<HD;++h){
    float a0 = sumh[r0][h], a1 = sumh[r0+1][h];
    float4 w = wtz4[h*HD4 + ob4];
    fma4(z0,a0,w); fma4(z1,a1,w);
  }
  z0 = sig4(z0); z1 = sig4(z1);

  const float4* br4 = (const float4*)br;
  const float4* wxr4 = (const float4*)wx_r;
  const float4* wtur4 = (const float4*)wt_ur;
  float4 rb0 = br4[ob4]; add4(rb0, wxr4[hp0*HD4 + ob4]);
  float4 rb1 = br4[ob4]; add4(rb1, wxr4[hp1*HD4 + ob4]);
  float4 sg0 = make_float4(0.f,0.f,0.f,0.f), sg1 = sg0;
  for (int k=0;k<KNEI;++k){
    __syncthreads();
    for (int idx=t; idx<8*HD4; idx+=512){
      int r = idx>>7, c = idx&127;
      hk4[idx] = hn4[((size_t)(n0+r)*KNEI + (size_t)k)*HD4 + c];
    }
    __syncthreads();
    float4 t0 = rb0, t1 = rb1;
    for (int h=0;h<HD;++h){
      float a0 = hk[r0][h], a1 = hk[r0+1][h];
      float4 w = wtur4[h*HD4 + ob4];
      fma4(t0,a0,w); fma4(t1,a1,w);
    }
    float4 e0 = hk4[r0*HD4 + ob4], e1 = hk4[(r0+1)*HD4 + ob4];
    add4(sg0, gate_mul(t0, e0));
    add4(sg1, gate_mul(t1, e1));
  }
  __syncthreads();
  sg4[r0*HD4+ob4] = sg0; sg4[(r0+1)*HD4+ob4] = sg1;
  __syncthreads();

  const float4* bh4 = (const float4*)bh;
  const float4* wxh4 = (const float4*)wx_h;
  const float4* wth4 = (const float4*)wt_h;
  float4 p0 = bh4[ob4]; add4(p0, wxh4[hp0*HD4+ob4]);
  float4 p1 = bh4[ob4]; add4(p1, wxh4[hp1*HD4+ob4]);
  for (int h=0;h<HD;++h){
    float a0 = sg[r0][h], a1 = sg[r0+1][h];
    float4 w = wth4[h*HD4+ob4];
    fma4(p0,a0,w); fma4(p1,a1,w);
  }
  float4 sh0 = sumh4[r0*HD4+ob4], sh1 = sumh4[(r0+1)*HD4+ob4];
  float4 m0 = gru_out(z0, sh0, p0);
  float4 m1 = gru_out(z1, sh1, p1);
  ((float4*)msg)[(size_t)(n0+r0)*HD4 + ob4] = m0;
  ((float4*)msg)[(size_t)(n0+r0+1)*HD4 + ob4] = m1;
  __syncthreads();
  sg4[r0*HD4+ob4] = m0; sg4[(r0+1)*HD4+ob4] = m1;
  __syncthreads();

  const float4* btnl4 = (const float4*)b_topo_nl;
  const float4* wttopo4 = (const float4*)wt_topo;
  float4 q0 = btnl4[ob4], q1 = btnl4[ob4];
  for (int h=0;h<HD;++h){
    float a0 = sg[r0][h], a1 = sg[r0+1][h];
    float4 w = wttopo4[h*HD4+ob4];
    fma4(q0,a0,w); fma4(q1,a1,w);
  }
  float4 wt4v = ((const float4*)w_topo)[ob4];
  float th0 = dot4(relu4(q0), wt4v);
  float th1 = dot4(relu4(q1), wt4v);
  #pragma unroll
  for (int s=32;s>0;s>>=1){ th0 += __shfl_down(th0,s); th1 += __shfl_down(th1,s); }
  if (lane==0){ red[r0][oh]=th0; red[r0+1][oh]=th1; }
  __syncthreads();
  if (t<8) out_stop[n0+t] = red[t][0] + red[t][1] + b_topo[0];
}

// ---------------- MFMA scan kernel with LDS DMA weight ring ----------------
// 64 blocks x 512 threads (8 waves), 32 rows/block, all 64 steps.
// Operand-swapped MFMA: A = weight frag (from ring), B = h^T (from hB LDS).
// D: lane holds col n = nt*16+(l&15), rows o = (4w+i)*16 + 4*(l>>4) + q.

__global__ __launch_bounds__(512, 2) void scan_ring_k(
    const int* __restrict__ nuc_idx,
    const float* __restrict__ msg,
    const short* __restrict__ stream,
    const short* __restrict__ fhpn,
    const float* __restrict__ wxbz, const float* __restrict__ wxbr, const float* __restrict__ wxbh,
    const float* __restrict__ latp,
    const float* __restrict__ w_nuc, const float* __restrict__ b_nuc,
    const float* __restrict__ b_hpn_nl, const float* __restrict__ w_hpn, const float* __restrict__ b_hpn,
    float* __restrict__ out_newh, float* __restrict__ out_hpn, float* __restrict__ out_nuc)
{
  __shared__ __align__(16) short stage[8][8][512];     // 64KB: per-wave 8-slot ring
  __shared__ __align__(16) short hB [32][HDP];         // bf16 h (33.3KB)
  __shared__ __align__(16) short hBg[32][HDP];         // bf16 gated-h (33.3KB)
  __shared__ unsigned short wxb_s[3][NNUC][HDP];       // bf16 bias tables (15.6KB)
  __shared__ unsigned short wns_s[NNUC][HD];           // bf16 nuc-out weights (5KB)
  __shared__ float redbuf[8][2][16][6];                // 6KB
  __shared__ int   codes[32];

  const int t = threadIdx.x, l = t&63, w = t>>6;
  const int lm = l&15, g = l>>4;
  const int n0 = blockIdx.x*32;

  // init staging
  for (int i=t;i<3*NNUC*HD;i+=512){
    int tb=i/(NNUC*HD), r2=i-tb*(NNUC*HD);
    const float* src = (tb==0)?wxbz:((tb==1)?wxbr:wxbh);
    wxb_s[tb][r2/HD][r2%HD] = f2bf(src[r2]);
  }
  for (int i=t;i<NNUC*HD;i+=512) wns_s[i/HD][i&511] = f2bf(w_nuc[i]);
  for (int i=t;i<32*HD;i+=512){
    int r2=i>>9, c=i&511;
    hB[r2][c] = (short)f2bf(msg[(size_t)(n0+r2)*HD + c]);
  }
  if (t<32) codes[t] = nuc_idx[(size_t)(n0+t)*LSEQ];
  float bn = 0.f;
  if (t<160) bn = b_nuc[t - (t/5)*5];

  // fp32 h master + packed lat_part in registers (lane-owned D positions)
  float hO[4][2][4];
  unsigned lpk[4][2][2];
  #pragma unroll
  for (int i=0;i<4;++i){
    #pragma unroll
    for (int nt=0;nt<2;++nt){
      size_t base = (size_t)(n0 + nt*16 + lm)*HD + (4*w+i)*16 + 4*g;
      float4 hv = *(const float4*)&msg[base];
      hO[i][nt][0]=hv.x; hO[i][nt][1]=hv.y; hO[i][nt][2]=hv.z; hO[i][nt][3]=hv.w;
      float4 lv = *(const float4*)&latp[base];
      lpk[i][nt][0] = (unsigned)f2bf(lv.x) | ((unsigned)f2bf(lv.y)<<16);
      lpk[i][nt][1] = (unsigned)f2bf(lv.z) | ((unsigned)f2bf(lv.w)<<16);
    }
  }
  __syncthreads();

  const short* glane = stream + (size_t)w*(256*512) + (size_t)l*8;
  // prologue: stage tiles 0..7
  issue4(glane, 0, &stage[w][0][0]);
  issue4(glane, 4, &stage[w][4][0]);

  f4 zacc[4][2], racc[4][2], cacc[4][2];

#define RING_SUB(ACC) { \
    WAITV4; \
    const short* sb = &stage[w][tt&7][0]; \
    s8b w0 = ((const s8b*)sb)[l]; \
    s8b w1 = ((const s8b*)(sb+512))[l]; \
    s8b w2 = ((const s8b*)(sb+1024))[l]; \
    s8b w3 = ((const s8b*)(sb+1536))[l]; \
    ACC[0][0]=MFMA16(w0,hb0,ACC[0][0]); ACC[0][1]=MFMA16(w0,hb1,ACC[0][1]); \
    ACC[1][0]=MFMA16(w1,hb0,ACC[1][0]); ACC[1][1]=MFMA16(w1,hb1,ACC[1][1]); \
    ACC[2][0]=MFMA16(w2,hb0,ACC[2][0]); ACC[2][1]=MFMA16(w2,hb1,ACC[2][1]); \
    ACC[3][0]=MFMA16(w3,hb0,ACC[3][0]); ACC[3][1]=MFMA16(w3,hb1,ACC[3][1]); \
    LGKM0; \
    issue4(glane, (tt+8)&255, sb); \
    tt += 4; }

  for (int step=0; step<LSEQ; ++step){
    int tt = 0;
    // zero accumulators
    #pragma unroll
    for (int i=0;i<4;++i){
      #pragma unroll
      for (int nt=0;nt<2;++nt){
        f4 zz; zz[0]=0.f; zz[1]=0.f; zz[2]=0.f; zz[3]=0.f;
        zacc[i][nt]=zz; racc[i][nt]=zz;
      }
    }
    // ---- z,r gemms (reads hB = h) ----
    #pragma unroll
    for (int kc=0;kc<16;++kc){
      s8b hb0 = *(const s8b*)&hB[lm][kc*32+g*8];
      s8b hb1 = *(const s8b*)&hB[16+lm][kc*32+g*8];
      RING_SUB(zacc);
      RING_SUB(racc);
    }
    // ---- gh epilogue ----
    {
      const int cd0 = codes[lm], cd1 = codes[16+lm];
      #pragma unroll
      for (int i=0;i<4;++i){
        const int ob = (4*w+i)*16 + 4*g;
        #pragma unroll
        for (int nt=0;nt<2;++nt){
          const int cd = nt ? cd1 : cd0;
          s4b pk;
          #pragma unroll
          for (int q=0;q<4;++q){
            const int o = ob + q;
            float zv = sigf(zacc[i][nt][q] + bf2f(wxb_s[0][cd][o]));
            float rv = sigf(racc[i][nt][q] + bf2f(wxb_s[1][cd][o]));
            float gh = rv * hO[i][nt][q];
            zacc[i][nt][q] = zv;            // keep z for combine
            pk[q] = (short)f2bf(gh);
          }
          *(s4b*)&hBg[nt*16+lm][ob] = pk;
        }
      }
    }
    BAR();  // gh visible
    // ---- candidate gemm (reads hBg) ----
    #pragma unroll
    for (int i=0;i<4;++i){
      #pragma unroll
      for (int nt=0;nt<2;++nt){ f4 zz; zz[0]=0.f; zz[1]=0.f; zz[2]=0.f; zz[3]=0.f; cacc[i][nt]=zz; }
    }
    #pragma unroll
    for (int kc=0;kc<16;++kc){
      s8b hb0 = *(const s8b*)&hBg[lm][kc*32+g*8];
      s8b hb1 = *(const s8b*)&hBg[16+lm][kc*32+g*8];
      RING_SUB(cacc);
    }
    // ---- h-update epilogue ----
    {
      const int cd0 = codes[lm], cd1 = codes[16+lm];
      #pragma unroll
      for (int i=0;i<4;++i){
        const int ob = (4*w+i)*16 + 4*g;
        #pragma unroll
        for (int nt=0;nt<2;++nt){
          const int cd = nt ? cd1 : cd0;
          s4b pk;
          #pragma unroll
          for (int q=0;q<4;++q){
            const int o = ob + q;
            float pre = tanhf_fast(cacc[i][nt][q] + bf2f(wxb_s[2][cd][o]));
            float zv  = zacc[i][nt][q];
            float hn  = (1.f - zv)*hO[i][nt][q] + zv*pre;
            hO[i][nt][q] = hn;
            pk[q] = (short)f2bf(hn);
          }
          *(s4b*)&hB[nt*16+lm][ob] = pk;
        }
      }
    }
    BAR();  // h_new visible
    if (t<32 && step+1<LSEQ) codes[t] = nuc_idx[(size_t)(n0+t)*LSEQ + step + 1];
    // ---- nuc head gemm (reads hB = h_new) ----
    #pragma unroll
    for (int i=0;i<4;++i){
      #pragma unroll
      for (int nt=0;nt<2;++nt){ f4 zz; zz[0]=0.f; zz[1]=0.f; zz[2]=0.f; zz[3]=0.f; cacc[i][nt]=zz; }
    }
    #pragma unroll
    for (int kc=0;kc<16;++kc){
      s8b hb0 = *(const s8b*)&hB[lm][kc*32+g*8];
      s8b hb1 = *(const s8b*)&hB[16+lm][kc*32+g*8];
      RING_SUB(cacc);
    }
    // ---- nuc epilogue: relu + tiny matvec + reduce ----
    {
      float p0[NNUC], p1[NNUC];
      #pragma unroll
      for (int j=0;j<NNUC;++j){ p0[j]=0.f; p1[j]=0.f; }
      #pragma unroll
      for (int i=0;i<4;++i){
        const int ob = (4*w+i)*16 + 4*g;
        #pragma unroll
        for (int q=0;q<4;++q){
          const int o = ob + q;
          float l0 = (q&1) ? bfhi(lpk[i][0][q>>1]) : bflo(lpk[i][0][q>>1]);
          float l1 = (q&1) ? bfhi(lpk[i][1][q>>1]) : bflo(lpk[i][1][q>>1]);
          float h0 = fmaxf(cacc[i][0][q] + l0, 0.f);
          float h1 = fmaxf(cacc[i][1][q] + l1, 0.f);
          #pragma unroll
          for (int j=0;j<NNUC;++j){
            float wv = bf2f(wns_s[j][o]);
            p0[j] = fmaf(h0, wv, p0[j]);
            p1[j] = fmaf(h1, wv, p1[j]);
          }
        }
      }
      #pragma unroll
      for (int j=0;j<NNUC;++j){
        p0[j] += __shfl_xor(p0[j],16); p0[j] += __shfl_xor(p0[j],32);
        p1[j] += __shfl_xor(p1[j],16); p1[j] += __shfl_xor(p1[j],32);
      }
      if (g==0){
        #pragma unroll
        for (int j=0;j<NNUC;++j){ redbuf[w][0][lm][j]=p0[j]; redbuf[w][1][lm][j]=p1[j]; }
      }
    }
    BAR();  // redbuf visible
    if (t < 32*NNUC){
      int r2 = t/NNUC, j = t - r2*NNUC;
      float s2 = 0.f;
      #pragma unroll
      for (int ww=0;ww<8;++ww) s2 += redbuf[ww][r2>>4][r2&15][j];
      out_nuc[((size_t)(n0+r2)*LSEQ + step)*NNUC + j] = s2 + bn;
    }
  }

  // ---- hpn head on final h (hB) ----
  {
    const s8b* fhB = (const s8b*)fhpn;
    f4 hacc[4][2];
    #pragma unroll
    for (int i=0;i<4;++i){
      #pragma unroll
      for (int nt=0;nt<2;++nt){ f4 zz; zz[0]=0.f; zz[1]=0.f; zz[2]=0.f; zz[3]=0.f; hacc[i][nt]=zz; }
    }
    #pragma unroll
    for (int kc=0;kc<16;++kc){
      s8b hb0 = *(const s8b*)&hB[lm][kc*32+g*8];
      s8b hb1 = *(const s8b*)&hB[16+lm][kc*32+g*8];
      #pragma unroll
      for (int i=0;i<4;++i){
        s8b wf = fhB[((4*w+i)*16+kc)*64 + l];
        hacc[i][0] = MFMA16(wf, hb0, hacc[i][0]);
        hacc[i][1] = MFMA16(wf, hb1, hacc[i][1]);
      }
    }
    float p0[NHPN], p1[NHPN];
    #pragma unroll
    for (int j=0;j<NHPN;++j){ p0[j]=0.f; p1[j]=0.f; }
    #pragma unroll
    for (int i=0;i<4;++i){
      const int ob = (4*w+i)*16 + 4*g;
      #pragma unroll
      for (int q=0;q<4;++q){
        const int o = ob + q;
        float bnl = b_hpn_nl[o];
        float h0 = fmaxf(hacc[i][0][q] + bnl, 0.f);
        float h1 = fmaxf(hacc[i][1][q] + bnl, 0.f);
        #pragma unroll
        for (int j=0;j<NHPN;++j){
          float wv = w_hpn[(size_t)j*HD + o];
          p0[j] = fmaf(h0, wv, p0[j]);
          p1[j] = fmaf(h1, wv, p1[j]);
        }
      }
    }
    #pragma unroll
    for (int j=0;j<NHPN;++j){
      p0[j] += __shfl_xor(p0[j],16); p0[j] += __shfl_xor(p0[j],32);
      p1[j] += __shfl_xor(p1[j],16); p1[j] += __shfl_xor(p1[j],32);
    }
    BAR();
    if (g==0){
      #pragma unroll
      for (int j=0;j<NHPN;++j){ redbuf[w][0][lm][j]=p0[j]; redbuf[w][1][lm][j]=p1[j]; }
    }
    BAR();
    if (t < 32*NHPN){
      int r2 = t/NHPN, j = t - r2*NHPN;
      float s2 = 0.f;
      #pragma unroll
      for (int ww=0;ww<8;++ww) s2 += redbuf[ww][r2>>4][r2&15][j];
      out_hpn[(size_t)(n0+r2)*NHPN + j] = s2 + b_hpn[j];
    }
  }

  // ---- write new_h from registers ----
  #pragma unroll
  for (int i=0;i<4;++i){
    #pragma unroll
    for (int nt=0;nt<2;++nt){
      size_t base = (size_t)(n0 + nt*16 + lm)*HD + (4*w+i)*16 + 4*g;
      float4 hv;
      hv.x=hO[i][nt][0]; hv.y=hO[i][nt][1]; hv.z=hO[i][nt][2]; hv.w=hO[i][nt][3];
      *(float4*)&out_newh[base] = hv;
    }
  }
}

// ---------------- host ----------------
extern "C" void kernel_launch(void* const* d_in, const int* in_sizes, int n_in,
                              void* d_out, int out_size, void* d_ws, size_t ws_size,
                              hipStream_t stream_){
  (void)in_sizes; (void)n_in; (void)out_size; (void)ws_size;
  const int*   hpn_idx      = (const int*)d_in[0];
  const int*   nuc_idx      = (const int*)d_in[1];
  const float* h_nei        = (const float*)d_in[2];
  const float* graph_latent = (const float*)d_in[3];
  const float* Wz_mp=(const float*)d_in[4];  const float* bz_mp=(const float*)d_in[5];
  const float* Wr_mp=(const float*)d_in[6];  const float* br_mp=(const float*)d_in[7];
  const float* Ur_mp=(const float*)d_in[8];
  const float* Wh_mp=(const float*)d_in[9];  const float* bh_mp=(const float*)d_in[10];
  const float* Wz_nuc=(const float*)d_in[11]; const float* bz_nuc=(const float*)d_in[12];
  const float* Wr_nuc=(const float*)d_in[13]; const float* br_nuc=(const float*)d_in[14];
  const float* Wh_nuc=(const float*)d_in[15]; const float* bh_nuc=(const float*)d_in[16];
  const float* W_hpn_nl=(const float*)d_in[17]; const float* b_hpn_nl=(const float*)d_in[18];
  const float* W_hpn=(const float*)d_in[19];  const float* b_hpn=(const float*)d_in[20];
  const float* W_nuc_nl=(const float*)d_in[21]; const float* b_nuc_nl=(const float*)d_in[22];
  const float* W_nuc=(const float*)d_in[23];  const float* b_nuc=(const float*)d_in[24];
  const float* W_topo_nl=(const float*)d_in[25]; const float* b_topo_nl=(const float*)d_in[26];
  const float* W_topo=(const float*)d_in[27]; const float* b_topo=(const float*)d_in[28];

  float* ws = (float*)d_ws;
  size_t off = 0;
  auto take = [&](size_t nfl){ float* p = ws + off; off += nfl; return p; };
  // graphgru fp32 transposed weights
  float* wt_z_mp   = take((size_t)HD*HD);
  float* wt_ur     = take((size_t)HD*HD);
  float* wt_h_mp   = take((size_t)HD*HD);
  float* wt_topo   = take((size_t)HD*HD);
  float* wt_nl_lat = take((size_t)LATD*HD);
  float* wx_z_mp   = take((size_t)NHPN*HD);
  float* wx_h_mp   = take((size_t)NHPN*HD);
  float* wx_r_mp   = take((size_t)NHPN*HD);
  // scan: flattened bf16 weight stream (8 waves x 256 tiles x 512 shorts)
  short* wstream   = (short*)take((size_t)8*256*512/2);
  short* fhpn      = (short*)take((size_t)HD*HD/2);
  float* wxbz = take((size_t)NNUC*HD);
  float* wxbr = take((size_t)NNUC*HD);
  float* wxbh = take((size_t)NNUC*HD);
  float* latp = take((size_t)NROWS*HD);
  float* msg  = take((size_t)NROWS*HD);

  float* out       = (float*)d_out;
  float* out_newh  = out;
  float* out_hpn   = out + (size_t)NROWS*HD;
  float* out_nuc   = out_hpn + (size_t)NROWS*NHPN;
  float* out_stop  = out_nuc + (size_t)NROWS*LSEQ*NNUC;

  auto T = [&](const float* src, float* dst, int sc, int coff, int nh){
    int total = nh*HD;
    transpose_w<<<(total+255)/256, 256, 0, stream_>>>(src, dst, sc, coff, nh);
  };
  T(Wz_mp,    wt_z_mp,   HD+NHPN, NHPN, HD);
  T(Wz_mp,    wx_z_mp,   HD+NHPN, 0,    NHPN);
  T(Wr_mp,    wx_r_mp,   NHPN,    0,    NHPN);
  T(Ur_mp,    wt_ur,     HD,      0,    HD);
  T(Wh_mp,    wt_h_mp,   HD+NHPN, NHPN, HD);
  T(Wh_mp,    wx_h_mp,   HD+NHPN, 0,    NHPN);
  T(W_topo_nl,wt_topo,   HD,      0,    HD);
  T(W_nuc_nl, wt_nl_lat, HD+LATD, HD,   LATD);

  streamprep_k<<<(8*256*512)/256, 256, 0, stream_>>>(Wz_nuc, Wr_nuc, Wh_nuc, W_nuc_nl, wstream);
  fragprep_k<<<(HD*HD+255)/256, 256, 0, stream_>>>(W_hpn_nl, fhpn, HD, 0);

  const int WB = (NNUC*HD+255)/256;
  wxbprep_k<<<WB,256,0,stream_>>>(Wz_nuc, bz_nuc, wxbz, HD+NNUC);
  wxbprep_k<<<WB,256,0,stream_>>>(Wr_nuc, br_nuc, wxbr, HD+NNUC);
  wxbprep_k<<<WB,256,0,stream_>>>(Wh_nuc, bh_nuc, wxbh, HD+NNUC);

  latp_k<<<NROWS/16, 512, 0, stream_>>>(graph_latent, wt_nl_lat, b_nuc_nl, latp);

  graphgru_k<<<NROWS/8, 512, 0, stream_>>>(
      hpn_idx, h_nei,
      wt_z_mp, wx_z_mp, bz_mp,
      wx_r_mp, br_mp, wt_ur,
      wt_h_mp, wx_h_mp, bh_mp,
      wt_topo, b_topo_nl, W_topo, b_topo,
      msg, out_stop);

  scan_ring_k<<<NROWS/32, 512, 0, stream_>>>(
      nuc_idx, msg, wstream, fhpn,
      wxbz, wxbr, wxbh, latp,
      W_nuc, b_nuc, b_hpn_nl, W_hpn, b_hpn,
      out_newh, out_hpn, out_nuc);
}